// Round 1
// baseline (495.023 us; speedup 1.0000x reference)
//
#include <hip/hip_runtime.h>
#include <hip/hip_bf16.h>

#define D_MODEL 1024
#define D_STATE 16
#define D_CONV  4
#define D_INNER 2048
#define BB      2
#define LL      1024
#define MM      (BB*LL)        // 2048 rows
#define NCH     16             // scan chunks
#define TC      (LL/NCH)       // 64 steps per chunk

typedef __attribute__((ext_vector_type(8))) short short8;   // 8 bf16
typedef __attribute__((ext_vector_type(4))) float float4v;

__device__ __forceinline__ ushort f2bf(float f) {
    unsigned u = __builtin_bit_cast(unsigned, f);
    u += 0x7fffu + ((u >> 16) & 1u);          // round-to-nearest-even
    return (ushort)(u >> 16);
}

// ---------------- LayerNorm -> bf16 ----------------
__global__ __launch_bounds__(256) void mb_ln(const float* __restrict__ x,
                                             const float* __restrict__ g,
                                             const float* __restrict__ b,
                                             ushort* __restrict__ xn) {
    int row = blockIdx.x;                       // 2048 rows
    const float* xr = x + (size_t)row * D_MODEL;
    float4 v = ((const float4*)xr)[threadIdx.x];
    float s  = v.x + v.y + v.z + v.w;
    float s2 = v.x*v.x + v.y*v.y + v.z*v.z + v.w*v.w;
    #pragma unroll
    for (int off = 32; off > 0; off >>= 1) {
        s  += __shfl_down(s, off);
        s2 += __shfl_down(s2, off);
    }
    __shared__ float w1[4], w2[4];
    if ((threadIdx.x & 63) == 0) { w1[threadIdx.x >> 6] = s; w2[threadIdx.x >> 6] = s2; }
    __syncthreads();
    s  = w1[0] + w1[1] + w1[2] + w1[3];
    s2 = w2[0] + w2[1] + w2[2] + w2[3];
    float mu  = s * (1.0f / D_MODEL);
    float var = s2 * (1.0f / D_MODEL) - mu * mu;
    float rs  = rsqrtf(var + 1e-5f);
    int i = threadIdx.x * 4;
    float vv[4] = {v.x, v.y, v.z, v.w};
    #pragma unroll
    for (int j = 0; j < 4; j++)
        xn[(size_t)row * D_MODEL + i + j] = f2bf((vv[j] - mu) * rs * g[i + j] + b[i + j]);
}

// ---------------- transpose fp32 [R,C] -> bf16 [C,R] ----------------
__global__ __launch_bounds__(256) void mb_transpose_cvt(const float* __restrict__ src,
                                                        ushort* __restrict__ dst,
                                                        int R, int C) {
    __shared__ float tile[32][33];
    int c0 = blockIdx.x * 32, r0 = blockIdx.y * 32;
    for (int i = threadIdx.y; i < 32; i += 8)
        tile[i][threadIdx.x] = src[(size_t)(r0 + i) * C + c0 + threadIdx.x];
    __syncthreads();
    for (int i = threadIdx.y; i < 32; i += 8)
        dst[(size_t)(c0 + i) * R + r0 + threadIdx.x] = f2bf(tile[threadIdx.x][i]);
}

// ---------------- bf16 MFMA GEMM: C[M,N] = A[M,K] * BT[N,K]^T (+ addsrc) ----------------
// block 256 = 4 waves, block tile 128x128, wave tile 64x64 = 4x4 mfma 16x16x32
__global__ __launch_bounds__(256) void mb_gemm_bf16(const ushort* __restrict__ A,
                                                    const ushort* __restrict__ BT,
                                                    float* __restrict__ C,
                                                    const float* __restrict__ addsrc,
                                                    int M, int N, int K) {
    __shared__ ushort As[128][32];
    __shared__ ushort Bs[128][32];
    int tid = threadIdx.x;
    int wave = tid >> 6, lane = tid & 63;
    int wm = (wave >> 1) * 64, wn = (wave & 1) * 64;
    int lr = lane & 15, quad = lane >> 4;
    int m0 = blockIdx.y * 128, n0 = blockIdx.x * 128;
    float4v acc[4][4] = {};

    for (int k0 = 0; k0 < K; k0 += 32) {
        #pragma unroll
        for (int i = 0; i < 2; i++) {
            int c = tid + 256 * i;
            int row = c >> 2, col = (c & 3) * 8;
            *(uint4*)(&As[row][col]) = *(const uint4*)(&A [(size_t)(m0 + row) * K + k0 + col]);
            *(uint4*)(&Bs[row][col]) = *(const uint4*)(&BT[(size_t)(n0 + row) * K + k0 + col]);
        }
        __syncthreads();
        short8 af[4], bf[4];
        #pragma unroll
        for (int i = 0; i < 4; i++) {
            af[i] = *(const short8*)(&As[wm + i * 16 + lr][quad * 8]);
            bf[i] = *(const short8*)(&Bs[wn + i * 16 + lr][quad * 8]);
        }
        #pragma unroll
        for (int mi = 0; mi < 4; mi++)
            #pragma unroll
            for (int ni = 0; ni < 4; ni++)
                acc[mi][ni] = __builtin_amdgcn_mfma_f32_16x16x32_bf16(af[mi], bf[ni], acc[mi][ni], 0, 0, 0);
        __syncthreads();
    }
    #pragma unroll
    for (int mi = 0; mi < 4; mi++)
        #pragma unroll
        for (int ni = 0; ni < 4; ni++)
            #pragma unroll
            for (int r = 0; r < 4; r++) {
                int m = m0 + wm + mi * 16 + quad * 4 + r;
                int n = n0 + wn + ni * 16 + lr;
                float v = acc[mi][ni][r];
                if (addsrc) v += addsrc[(size_t)m * N + n];
                C[(size_t)m * N + n] = v;
            }
}

// ---------------- causal depthwise conv(4) + SiLU ----------------
__global__ __launch_bounds__(256) void mb_conv_silu(const float* __restrict__ xz,
                                                    const float* __restrict__ cw,
                                                    const float* __restrict__ cb,
                                                    float* __restrict__ xc) {
    int idx = blockIdx.x * 256 + threadIdx.x;   // B*L*D_INNER
    int d = idx & (D_INNER - 1);
    int bl = idx >> 11;
    int l = bl & (LL - 1);
    int b = bl >> 10;
    float acc = cb[d];
    #pragma unroll
    for (int j = 0; j < 4; j++) {
        int ls = l - 3 + j;
        if (ls >= 0)
            acc += xz[((size_t)(b * LL + ls)) * (2 * D_INNER) + d] * cw[d * 4 + j];
    }
    float sig = 1.0f / (1.0f + __expf(-acc));
    xc[idx] = acc * sig;
}

// ---------------- small GEMM: bcdt[m,e] = xc[m,:] @ W_x[:,e], e<33 ----------------
__global__ __launch_bounds__(64) void mb_small_gemm(const float* __restrict__ xc,
                                                    const float* __restrict__ Wx,
                                                    float* __restrict__ bcdt) {
    int m = blockIdx.x;
    int e = threadIdx.x;
    const float* xr = xc + (size_t)m * D_INNER;
    float acc = 0.f;
    for (int k = 0; k < D_INNER; k += 4) {
        float4 xv = *(const float4*)(xr + k);
        if (e < 33) {
            acc += xv.x * Wx[(k    ) * 33 + e];
            acc += xv.y * Wx[(k + 1) * 33 + e];
            acc += xv.z * Wx[(k + 2) * 33 + e];
            acc += xv.w * Wx[(k + 3) * 33 + e];
        }
    }
    if (e < 33) bcdt[(size_t)m * 33 + e] = acc;
}

// ---------------- dt = softplus(dt_raw * w_dt + b_dt) ----------------
__global__ __launch_bounds__(256) void mb_dt(const float* __restrict__ bcdt,
                                             const float* __restrict__ wdt,
                                             const float* __restrict__ bdt,
                                             float* __restrict__ dt) {
    int idx = blockIdx.x * 256 + threadIdx.x;
    int d = idx & (D_INNER - 1);
    int bl = idx >> 11;
    float xv = bcdt[(size_t)bl * 33] * wdt[d] + bdt[d];
    dt[idx] = (xv > 20.f) ? xv : log1pf(__expf(xv));
}

// ---------------- scan phase 1: per-chunk local h_end + sum(dt) ----------------
__global__ __launch_bounds__(256) void mb_scan1(const float* __restrict__ dt,
                                                const float* __restrict__ xc,
                                                const float* __restrict__ bcdt,
                                                const float* __restrict__ A_log,
                                                float* __restrict__ hend,
                                                float* __restrict__ dtsum) {
    int d = blockIdx.x * 256 + threadIdx.x;
    int c = blockIdx.y, b = blockIdx.z;
    int t0 = c * TC;
    __shared__ float Bl[TC][16];
    for (int i = threadIdx.x; i < TC * 16; i += 256) {
        int t = i >> 4, s = i & 15;
        Bl[t][s] = bcdt[((size_t)(b * LL) + t0 + t) * 33 + 1 + s];
    }
    __syncthreads();
    float A[16];
    #pragma unroll
    for (int s = 0; s < 16; s++) A[s] = -__expf(A_log[d * 16 + s]);
    float h[16] = {};
    float ds = 0.f;
    size_t base = ((size_t)b * LL + t0) * D_INNER + d;
    for (int t = 0; t < TC; t++) {
        float dtv = dt[base + (size_t)t * D_INNER];
        float xcv = xc[base + (size_t)t * D_INNER];
        float dx = dtv * xcv;
        ds += dtv;
        #pragma unroll
        for (int s = 0; s < 16; s++) {
            float dA = __expf(dtv * A[s]);
            h[s] = dA * h[s] + dx * Bl[t][s];
        }
    }
    size_t hb = (((size_t)b * NCH + c) * D_INNER + d) * 16;
    #pragma unroll
    for (int s = 0; s < 16; s++) hend[hb + s] = h[s];
    dtsum[((size_t)b * NCH + c) * D_INNER + d] = ds;
}

// ---------------- scan phase 2: sequential chunk combine ----------------
__global__ __launch_bounds__(256) void mb_scan2(const float* __restrict__ hend,
                                                const float* __restrict__ dtsum,
                                                const float* __restrict__ A_log,
                                                float* __restrict__ hstart) {
    int idx = blockIdx.x * 256 + threadIdx.x;   // B*D_INNER*16
    int s = idx & 15;
    int d = (idx >> 4) & (D_INNER - 1);
    int b = idx >> 15;
    float A = -__expf(A_log[d * 16 + s]);
    float h = 0.f;
    for (int c = 0; c < NCH; c++) {
        size_t o = (((size_t)b * NCH + c) * D_INNER + d) * 16 + s;
        hstart[o] = h;
        h = __expf(A * dtsum[((size_t)b * NCH + c) * D_INNER + d]) * h + hend[o];
    }
}

// ---------------- scan phase 3: full scan per chunk + y + gating -> bf16 ----------------
__global__ __launch_bounds__(256) void mb_scan3(const float* __restrict__ dt,
                                                const float* __restrict__ xc,
                                                const float* __restrict__ bcdt,
                                                const float* __restrict__ A_log,
                                                const float* __restrict__ hstart,
                                                const float* __restrict__ Dp,
                                                const float* __restrict__ xz,
                                                ushort* __restrict__ ybf) {
    int d = blockIdx.x * 256 + threadIdx.x;
    int c = blockIdx.y, b = blockIdx.z;
    int t0 = c * TC;
    __shared__ float Bl[TC][16], Cl[TC][16];
    for (int i = threadIdx.x; i < TC * 16; i += 256) {
        int t = i >> 4, s = i & 15;
        size_t ro = ((size_t)(b * LL) + t0 + t) * 33;
        Bl[t][s] = bcdt[ro + 1 + s];
        Cl[t][s] = bcdt[ro + 17 + s];
    }
    __syncthreads();
    float A[16], h[16];
    #pragma unroll
    for (int s = 0; s < 16; s++) A[s] = -__expf(A_log[d * 16 + s]);
    size_t hb = (((size_t)b * NCH + c) * D_INNER + d) * 16;
    #pragma unroll
    for (int s = 0; s < 16; s++) h[s] = hstart[hb + s];
    float Dv = Dp[d];
    size_t base  = ((size_t)b * LL + t0) * D_INNER + d;
    size_t zbase = ((size_t)b * LL + t0) * (2 * D_INNER) + D_INNER + d;
    for (int t = 0; t < TC; t++) {
        float dtv = dt[base + (size_t)t * D_INNER];
        float xcv = xc[base + (size_t)t * D_INNER];
        float dx = dtv * xcv;
        float y = 0.f;
        #pragma unroll
        for (int s = 0; s < 16; s++) {
            float dA = __expf(dtv * A[s]);
            h[s] = dA * h[s] + dx * Bl[t][s];
            y += h[s] * Cl[t][s];
        }
        float zv = xz[zbase + (size_t)t * (2 * D_INNER)];
        float sig = 1.0f / (1.0f + __expf(-zv));
        float yg = (y + xcv * Dv) * (zv * sig);
        ybf[base + (size_t)t * D_INNER] = f2bf(yg);
    }
}

extern "C" void kernel_launch(void* const* d_in, const int* in_sizes, int n_in,
                              void* d_out, int out_size, void* d_ws, size_t ws_size,
                              hipStream_t stream) {
    const float* x      = (const float*)d_in[0];
    const float* ln_g   = (const float*)d_in[1];
    const float* ln_b   = (const float*)d_in[2];
    const float* W_in   = (const float*)d_in[3];
    const float* conv_w = (const float*)d_in[4];
    const float* conv_b = (const float*)d_in[5];
    const float* W_x    = (const float*)d_in[6];
    const float* w_dt   = (const float*)d_in[7];
    const float* b_dt   = (const float*)d_in[8];
    const float* A_log  = (const float*)d_in[9];
    const float* D_par  = (const float*)d_in[10];
    const float* W_out  = (const float*)d_in[11];
    float* out = (float*)d_out;

    char* w = (char*)d_ws;
    ushort* xn    = (ushort*)w; w += (size_t)MM * D_MODEL * 2;            // 4 MB
    ushort* WinT  = (ushort*)w; w += (size_t)(2 * D_INNER) * D_MODEL * 2; // 8 MB
    ushort* WoutT = (ushort*)w; w += (size_t)D_MODEL * D_INNER * 2;       // 4 MB
    float*  xz    = (float*)w;  w += (size_t)MM * (2 * D_INNER) * 4;      // 32 MB
    float*  xc    = (float*)w;  w += (size_t)MM * D_INNER * 4;            // 16 MB
    float*  dtw   = (float*)w;  w += (size_t)MM * D_INNER * 4;            // 16 MB
    float*  bcdt  = (float*)w;  w += (size_t)MM * 33 * 4 + 128;           // ~270 KB
    float*  hend  = (float*)w;  w += (size_t)BB * NCH * D_INNER * 16 * 4; // 4 MB
    float*  hstart= (float*)w;  w += (size_t)BB * NCH * D_INNER * 16 * 4; // 4 MB
    float*  dtsum = (float*)w;  w += (size_t)BB * NCH * D_INNER * 4;      // 256 KB
    ushort* ybf   = (ushort*)w; w += (size_t)MM * D_INNER * 2;            // 8 MB

    mb_ln<<<MM, 256, 0, stream>>>(x, ln_g, ln_b, xn);
    mb_transpose_cvt<<<dim3((2 * D_INNER) / 32, D_MODEL / 32), dim3(32, 8), 0, stream>>>(
        W_in, WinT, D_MODEL, 2 * D_INNER);
    mb_transpose_cvt<<<dim3(D_MODEL / 32, D_INNER / 32), dim3(32, 8), 0, stream>>>(
        W_out, WoutT, D_INNER, D_MODEL);
    mb_gemm_bf16<<<dim3((2 * D_INNER) / 128, MM / 128), 256, 0, stream>>>(
        xn, WinT, xz, nullptr, MM, 2 * D_INNER, D_MODEL);
    mb_conv_silu<<<(MM * D_INNER) / 256, 256, 0, stream>>>(xz, conv_w, conv_b, xc);
    mb_small_gemm<<<MM, 64, 0, stream>>>(xc, W_x, bcdt);
    mb_dt<<<(MM * D_INNER) / 256, 256, 0, stream>>>(bcdt, w_dt, b_dt, dtw);
    mb_scan1<<<dim3(D_INNER / 256, NCH, BB), 256, 0, stream>>>(dtw, xc, bcdt, A_log, hend, dtsum);
    mb_scan2<<<(BB * D_INNER * 16) / 256, 256, 0, stream>>>(hend, dtsum, A_log, hstart);
    mb_scan3<<<dim3(D_INNER / 256, NCH, BB), 256, 0, stream>>>(dtw, xc, bcdt, A_log, hstart,
                                                               D_par, xz, ybf);
    mb_gemm_bf16<<<dim3(D_MODEL / 128, MM / 128), 256, 0, stream>>>(
        ybf, WoutT, out, x, MM, D_MODEL, D_INNER);
}

// Round 2
// 333.199 us; speedup vs baseline: 1.4857x; 1.4857x over previous
//
#include <hip/hip_runtime.h>
#include <hip/hip_bf16.h>

#define D_MODEL 1024
#define D_STATE 16
#define D_CONV  4
#define D_INNER 2048
#define BB      2
#define LL      1024
#define MM      (BB*LL)        // 2048 rows
#define NCH     16             // scan chunks
#define TC      (LL/NCH)       // 64 steps per chunk
#define NPAD    48             // padded N for bcdt GEMM (33 -> 48)

typedef __attribute__((ext_vector_type(8))) short short8;   // 8 bf16
typedef __attribute__((ext_vector_type(4))) float float4v;

__device__ __forceinline__ ushort f2bf(float f) {
    unsigned u = __builtin_bit_cast(unsigned, f);
    u += 0x7fffu + ((u >> 16) & 1u);          // round-to-nearest-even
    return (ushort)(u >> 16);
}
__device__ __forceinline__ float bf2f(ushort u) {
    return __builtin_bit_cast(float, ((unsigned)u) << 16);
}

// ---------------- LayerNorm -> bf16 ----------------
__global__ __launch_bounds__(256) void mb_ln(const float* __restrict__ x,
                                             const float* __restrict__ g,
                                             const float* __restrict__ b,
                                             ushort* __restrict__ xn) {
    int row = blockIdx.x;                       // 2048 rows
    const float* xr = x + (size_t)row * D_MODEL;
    float4 v = ((const float4*)xr)[threadIdx.x];
    float s  = v.x + v.y + v.z + v.w;
    float s2 = v.x*v.x + v.y*v.y + v.z*v.z + v.w*v.w;
    #pragma unroll
    for (int off = 32; off > 0; off >>= 1) {
        s  += __shfl_down(s, off);
        s2 += __shfl_down(s2, off);
    }
    __shared__ float w1[4], w2[4];
    if ((threadIdx.x & 63) == 0) { w1[threadIdx.x >> 6] = s; w2[threadIdx.x >> 6] = s2; }
    __syncthreads();
    s  = w1[0] + w1[1] + w1[2] + w1[3];
    s2 = w2[0] + w2[1] + w2[2] + w2[3];
    float mu  = s * (1.0f / D_MODEL);
    float var = s2 * (1.0f / D_MODEL) - mu * mu;
    float rs  = rsqrtf(var + 1e-5f);
    int i = threadIdx.x * 4;
    float vv[4] = {v.x, v.y, v.z, v.w};
    #pragma unroll
    for (int j = 0; j < 4; j++)
        xn[(size_t)row * D_MODEL + i + j] = f2bf((vv[j] - mu) * rs * g[i + j] + b[i + j]);
}

// ---------------- transpose fp32 [R,C] -> bf16 [C,R] ----------------
__global__ __launch_bounds__(256) void mb_transpose_cvt(const float* __restrict__ src,
                                                        ushort* __restrict__ dst,
                                                        int R, int C) {
    __shared__ float tile[32][33];
    int c0 = blockIdx.x * 32, r0 = blockIdx.y * 32;
    for (int i = threadIdx.y; i < 32; i += 8)
        tile[i][threadIdx.x] = src[(size_t)(r0 + i) * C + c0 + threadIdx.x];
    __syncthreads();
    for (int i = threadIdx.y; i < 32; i += 8)
        dst[(size_t)(c0 + i) * R + r0 + threadIdx.x] = f2bf(tile[threadIdx.x][i]);
}

// ---------------- prep: W_x^T -> bf16 [48][2048] (zero-pad) + zero bcdt ----------------
__global__ __launch_bounds__(256) void mb_prep(const float* __restrict__ Wx,
                                               ushort* __restrict__ WxT,
                                               float* __restrict__ bcdt) {
    int idx = blockIdx.x * 256 + threadIdx.x;   // 48*2048 == 2048*48
    int n = idx >> 11, k = idx & 2047;
    WxT[idx] = (n < 33) ? f2bf(Wx[(size_t)k * 33 + n]) : (ushort)0;
    bcdt[idx] = 0.f;
}

// ---------------- bf16 MFMA GEMM: C[M,N] = A[M,K] * BT[N,K]^T (+ addsrc) ----------------
__global__ __launch_bounds__(256) void mb_gemm_bf16(const ushort* __restrict__ A,
                                                    const ushort* __restrict__ BT,
                                                    float* __restrict__ C,
                                                    const float* __restrict__ addsrc,
                                                    int M, int N, int K) {
    __shared__ ushort As[128][32];
    __shared__ ushort Bs[128][32];
    int tid = threadIdx.x;
    int wave = tid >> 6, lane = tid & 63;
    int wm = (wave >> 1) * 64, wn = (wave & 1) * 64;
    int lr = lane & 15, quad = lane >> 4;
    int m0 = blockIdx.y * 128, n0 = blockIdx.x * 128;
    float4v acc[4][4] = {};

    for (int k0 = 0; k0 < K; k0 += 32) {
        #pragma unroll
        for (int i = 0; i < 2; i++) {
            int c = tid + 256 * i;
            int row = c >> 2, col = (c & 3) * 8;
            *(uint4*)(&As[row][col]) = *(const uint4*)(&A [(size_t)(m0 + row) * K + k0 + col]);
            *(uint4*)(&Bs[row][col]) = *(const uint4*)(&BT[(size_t)(n0 + row) * K + k0 + col]);
        }
        __syncthreads();
        short8 af[4], bf[4];
        #pragma unroll
        for (int i = 0; i < 4; i++) {
            af[i] = *(const short8*)(&As[wm + i * 16 + lr][quad * 8]);
            bf[i] = *(const short8*)(&Bs[wn + i * 16 + lr][quad * 8]);
        }
        #pragma unroll
        for (int mi = 0; mi < 4; mi++)
            #pragma unroll
            for (int ni = 0; ni < 4; ni++)
                acc[mi][ni] = __builtin_amdgcn_mfma_f32_16x16x32_bf16(af[mi], bf[ni], acc[mi][ni], 0, 0, 0);
        __syncthreads();
    }
    #pragma unroll
    for (int mi = 0; mi < 4; mi++)
        #pragma unroll
        for (int ni = 0; ni < 4; ni++)
            #pragma unroll
            for (int r = 0; r < 4; r++) {
                int m = m0 + wm + mi * 16 + quad * 4 + r;
                int n = n0 + wn + ni * 16 + lr;
                float v = acc[mi][ni][r];
                if (addsrc) v += addsrc[(size_t)m * N + n];
                C[(size_t)m * N + n] = v;
            }
}

// ---------------- causal depthwise conv(4) + SiLU -> bf16 ----------------
__global__ __launch_bounds__(256) void mb_conv_silu(const float* __restrict__ xz,
                                                    const float* __restrict__ cw,
                                                    const float* __restrict__ cb,
                                                    ushort* __restrict__ xcb) {
    int idx = blockIdx.x * 256 + threadIdx.x;   // B*L*D_INNER
    int d = idx & (D_INNER - 1);
    int bl = idx >> 11;
    int l = bl & (LL - 1);
    int b = bl >> 10;
    float acc = cb[d];
    #pragma unroll
    for (int j = 0; j < 4; j++) {
        int ls = l - 3 + j;
        if (ls >= 0)
            acc += xz[((size_t)(b * LL + ls)) * (2 * D_INNER) + d] * cw[d * 4 + j];
    }
    float sig = 1.0f / (1.0f + __expf(-acc));
    xcb[idx] = f2bf(acc * sig);
}

// ---------------- skinny MFMA GEMM: bcdt[M][48] += xcb[M,K] @ WxT[48,K]^T ----------------
// grid (KSPLIT=8, MBLK=32), block 256 = 4 waves, wave tile 16x48, fragments straight from global
__global__ __launch_bounds__(256) void mb_bcdt_gemm(const ushort* __restrict__ xcb,
                                                    const ushort* __restrict__ WxT,
                                                    float* __restrict__ bcdt) {
    int wave = threadIdx.x >> 6, lane = threadIdx.x & 63;
    int lr = lane & 15, quad = lane >> 4;
    int m0 = blockIdx.y * 64 + wave * 16;
    int k0 = blockIdx.x * 256;
    float4v acc[3] = {};
    #pragma unroll
    for (int kk = 0; kk < 256; kk += 32) {
        short8 a = *(const short8*)(xcb + (size_t)(m0 + lr) * D_INNER + k0 + kk + quad * 8);
        #pragma unroll
        for (int ni = 0; ni < 3; ni++) {
            short8 b = *(const short8*)(WxT + (size_t)(ni * 16 + lr) * D_INNER + k0 + kk + quad * 8);
            acc[ni] = __builtin_amdgcn_mfma_f32_16x16x32_bf16(a, b, acc[ni], 0, 0, 0);
        }
    }
    #pragma unroll
    for (int ni = 0; ni < 3; ni++)
        #pragma unroll
        for (int r = 0; r < 4; r++) {
            int n = ni * 16 + lr;
            if (n < 33)
                atomicAdd(&bcdt[(size_t)(m0 + quad * 4 + r) * NPAD + n], acc[ni][r]);
        }
}

// ---------------- scan phase 1: per-chunk local h_end + sum(dt) ----------------
__global__ __launch_bounds__(256) void mb_scan1(const ushort* __restrict__ xcb,
                                                const float* __restrict__ bcdt,
                                                const float* __restrict__ A_log,
                                                const float* __restrict__ wdt,
                                                const float* __restrict__ bdt,
                                                float* __restrict__ hend,
                                                float* __restrict__ dtsum) {
    int d = blockIdx.x * 256 + threadIdx.x;
    int c = blockIdx.y, b = blockIdx.z;
    int t0 = c * TC;
    __shared__ float Bl[TC][16];
    __shared__ float draw[TC];
    for (int i = threadIdx.x; i < TC * 16; i += 256) {
        int t = i >> 4, s = i & 15;
        Bl[t][s] = bcdt[((size_t)(b * LL) + t0 + t) * NPAD + 1 + s];
    }
    if (threadIdx.x < TC)
        draw[threadIdx.x] = bcdt[((size_t)(b * LL) + t0 + threadIdx.x) * NPAD];
    __syncthreads();
    float A[16];
    #pragma unroll
    for (int s = 0; s < 16; s++) A[s] = -__expf(A_log[d * 16 + s]);
    float wd = wdt[d], bd = bdt[d];
    float h[16] = {};
    float ds = 0.f;
    size_t base = ((size_t)b * LL + t0) * D_INNER + d;
    for (int t = 0; t < TC; t++) {
        float v = draw[t] * wd + bd;
        float dtv = (v > 20.f) ? v : log1pf(__expf(v));
        float xcv = bf2f(xcb[base + (size_t)t * D_INNER]);
        float dx = dtv * xcv;
        ds += dtv;
        #pragma unroll
        for (int s = 0; s < 16; s++) {
            float dA = __expf(dtv * A[s]);
            h[s] = dA * h[s] + dx * Bl[t][s];
        }
    }
    size_t hb = (((size_t)b * NCH + c) * D_INNER + d) * 16;
    #pragma unroll
    for (int s = 0; s < 16; s++) hend[hb + s] = h[s];
    dtsum[((size_t)b * NCH + c) * D_INNER + d] = ds;
}

// ---------------- scan phase 2: sequential chunk combine ----------------
__global__ __launch_bounds__(256) void mb_scan2(const float* __restrict__ hend,
                                                const float* __restrict__ dtsum,
                                                const float* __restrict__ A_log,
                                                float* __restrict__ hstart) {
    int idx = blockIdx.x * 256 + threadIdx.x;   // B*D_INNER*16
    int s = idx & 15;
    int d = (idx >> 4) & (D_INNER - 1);
    int b = idx >> 15;
    float A = -__expf(A_log[d * 16 + s]);
    float h = 0.f;
    for (int c = 0; c < NCH; c++) {
        size_t o = (((size_t)b * NCH + c) * D_INNER + d) * 16 + s;
        hstart[o] = h;
        h = __expf(A * dtsum[((size_t)b * NCH + c) * D_INNER + d]) * h + hend[o];
    }
}

// ---------------- scan phase 3: full scan per chunk + y + gating -> bf16 ----------------
__global__ __launch_bounds__(256) void mb_scan3(const ushort* __restrict__ xcb,
                                                const float* __restrict__ bcdt,
                                                const float* __restrict__ A_log,
                                                const float* __restrict__ wdt,
                                                const float* __restrict__ bdt,
                                                const float* __restrict__ hstart,
                                                const float* __restrict__ Dp,
                                                const float* __restrict__ xz,
                                                ushort* __restrict__ ybf) {
    int d = blockIdx.x * 256 + threadIdx.x;
    int c = blockIdx.y, b = blockIdx.z;
    int t0 = c * TC;
    __shared__ float Bl[TC][16], Cl[TC][16];
    __shared__ float draw[TC];
    for (int i = threadIdx.x; i < TC * 16; i += 256) {
        int t = i >> 4, s = i & 15;
        size_t ro = ((size_t)(b * LL) + t0 + t) * NPAD;
        Bl[t][s] = bcdt[ro + 1 + s];
        Cl[t][s] = bcdt[ro + 17 + s];
    }
    if (threadIdx.x < TC)
        draw[threadIdx.x] = bcdt[((size_t)(b * LL) + t0 + threadIdx.x) * NPAD];
    __syncthreads();
    float A[16], h[16];
    #pragma unroll
    for (int s = 0; s < 16; s++) A[s] = -__expf(A_log[d * 16 + s]);
    size_t hb = (((size_t)b * NCH + c) * D_INNER + d) * 16;
    #pragma unroll
    for (int s = 0; s < 16; s++) h[s] = hstart[hb + s];
    float wd = wdt[d], bd = bdt[d];
    float Dv = Dp[d];
    size_t base  = ((size_t)b * LL + t0) * D_INNER + d;
    size_t zbase = ((size_t)b * LL + t0) * (2 * D_INNER) + D_INNER + d;
    for (int t = 0; t < TC; t++) {
        float v = draw[t] * wd + bd;
        float dtv = (v > 20.f) ? v : log1pf(__expf(v));
        float xcv = bf2f(xcb[base + (size_t)t * D_INNER]);
        float dx = dtv * xcv;
        float y = 0.f;
        #pragma unroll
        for (int s = 0; s < 16; s++) {
            float dA = __expf(dtv * A[s]);
            h[s] = dA * h[s] + dx * Bl[t][s];
            y += h[s] * Cl[t][s];
        }
        float zv = xz[zbase + (size_t)t * (2 * D_INNER)];
        float sig = 1.0f / (1.0f + __expf(-zv));
        float yg = (y + xcv * Dv) * (zv * sig);
        ybf[base + (size_t)t * D_INNER] = f2bf(yg);
    }
}

extern "C" void kernel_launch(void* const* d_in, const int* in_sizes, int n_in,
                              void* d_out, int out_size, void* d_ws, size_t ws_size,
                              hipStream_t stream) {
    const float* x      = (const float*)d_in[0];
    const float* ln_g   = (const float*)d_in[1];
    const float* ln_b   = (const float*)d_in[2];
    const float* W_in   = (const float*)d_in[3];
    const float* conv_w = (const float*)d_in[4];
    const float* conv_b = (const float*)d_in[5];
    const float* W_x    = (const float*)d_in[6];
    const float* w_dt   = (const float*)d_in[7];
    const float* b_dt   = (const float*)d_in[8];
    const float* A_log  = (const float*)d_in[9];
    const float* D_par  = (const float*)d_in[10];
    const float* W_out  = (const float*)d_in[11];
    float* out = (float*)d_out;

    char* w = (char*)d_ws;
    ushort* xn    = (ushort*)w; w += (size_t)MM * D_MODEL * 2;            // 4 MB
    ushort* WinT  = (ushort*)w; w += (size_t)(2 * D_INNER) * D_MODEL * 2; // 8 MB
    ushort* WoutT = (ushort*)w; w += (size_t)D_MODEL * D_INNER * 2;       // 4 MB
    float*  xz    = (float*)w;  w += (size_t)MM * (2 * D_INNER) * 4;      // 32 MB
    ushort* xcb   = (ushort*)w; w += (size_t)MM * D_INNER * 2;            // 8 MB
    ushort* WxT   = (ushort*)w; w += (size_t)NPAD * D_INNER * 2;          // 192 KB
    float*  bcdt  = (float*)w;  w += (size_t)MM * NPAD * 4;              // 384 KB
    float*  hend  = (float*)w;  w += (size_t)BB * NCH * D_INNER * 16 * 4; // 4 MB
    float*  hstart= (float*)w;  w += (size_t)BB * NCH * D_INNER * 16 * 4; // 4 MB
    float*  dtsum = (float*)w;  w += (size_t)BB * NCH * D_INNER * 4;      // 256 KB
    ushort* ybf   = (ushort*)w; w += (size_t)MM * D_INNER * 2;            // 8 MB

    mb_ln<<<MM, 256, 0, stream>>>(x, ln_g, ln_b, xn);
    mb_transpose_cvt<<<dim3((2 * D_INNER) / 32, D_MODEL / 32), dim3(32, 8), 0, stream>>>(
        W_in, WinT, D_MODEL, 2 * D_INNER);
    mb_transpose_cvt<<<dim3(D_MODEL / 32, D_INNER / 32), dim3(32, 8), 0, stream>>>(
        W_out, WoutT, D_INNER, D_MODEL);
    mb_prep<<<(NPAD * D_INNER) / 256, 256, 0, stream>>>(W_x, WxT, bcdt);
    mb_gemm_bf16<<<dim3((2 * D_INNER) / 128, MM / 128), 256, 0, stream>>>(
        xn, WinT, xz, nullptr, MM, 2 * D_INNER, D_MODEL);
    mb_conv_silu<<<(MM * D_INNER) / 256, 256, 0, stream>>>(xz, conv_w, conv_b, xcb);
    mb_bcdt_gemm<<<dim3(8, MM / 64), 256, 0, stream>>>(xcb, WxT, bcdt);
    mb_scan1<<<dim3(D_INNER / 256, NCH, BB), 256, 0, stream>>>(xcb, bcdt, A_log, w_dt, b_dt,
                                                               hend, dtsum);
    mb_scan2<<<(BB * D_INNER * 16) / 256, 256, 0, stream>>>(hend, dtsum, A_log, hstart);
    mb_scan3<<<dim3(D_INNER / 256, NCH, BB), 256, 0, stream>>>(xcb, bcdt, A_log, w_dt, b_dt,
                                                               hstart, D_par, xz, ybf);
    mb_gemm_bf16<<<dim3(D_MODEL / 128, MM / 128), 256, 0, stream>>>(
        ybf, WoutT, out, x, MM, D_MODEL, D_INNER);
}